// Round 8
// baseline (232.430 us; speedup 1.0000x reference)
//
#include <hip/hip_runtime.h>
#include <hip/hip_bf16.h>

typedef __attribute__((ext_vector_type(8))) short short8;
typedef __attribute__((ext_vector_type(4))) short bf16x4;
typedef __attribute__((ext_vector_type(4))) float floatx4;

#define MFMA16(a, b, c) __builtin_amdgcn_mfma_f32_16x16x32_bf16((a), (b), (c), 0, 0, 0)

#if defined(__has_builtin)
#if __has_builtin(__builtin_amdgcn_mfma_f32_16x16x16_bf16)
#define HAVE_PV16 1
#define MFMA_PV(a, b, c) __builtin_amdgcn_mfma_f32_16x16x16_bf16((a), (b), (c), 0, 0, 0)
#elif __has_builtin(__builtin_amdgcn_mfma_f32_16x16x16bf16_1k)
#define HAVE_PV16 1
#define MFMA_PV(a, b, c) __builtin_amdgcn_mfma_f32_16x16x16bf16_1k((a), (b), (c), 0, 0, 0)
#else
#define HAVE_PV16 0
#endif
#else
#define HAVE_PV16 0
#endif

#define SEQ    2048
#define DIMM   1024
#define HEADS  16
#define DHEAD  64
#define ROWS   4096      // b*n = 2*2048
// fixed-max softmax: p = exp2(s*K1 + K2), K1 = 0.125*log2(e), K2 = -24*log2(e)
#define K1 0.18033688011112043f
#define K2 (-34.62468098133512f)

// ---------------------------------------------------------------------------
// Prep kernels (run once, tiny): fp32 -> bf16 copy; fp32 -> bf16 transpose.
// ---------------------------------------------------------------------------
__global__ void cvt_bf16_kernel(const float* __restrict__ src,
                                __hip_bfloat16* __restrict__ dst) {
    const size_t i = (size_t)(blockIdx.x * 256 + threadIdx.x) * 4;
    floatx4 v = *(const floatx4*)(src + i);
    union { bf16x4 s; __hip_bfloat16 h[4]; } u;
#pragma unroll
    for (int j = 0; j < 4; j++) u.h[j] = __float2bfloat16(v[j]);
    *(bf16x4*)(dst + i) = u.s;
}

__global__ void transpose_cvt_kernel(const float* __restrict__ W,
                                     __hip_bfloat16* __restrict__ WT, int ld) {
    const int idx = blockIdx.x * 256 + threadIdx.x;   // over 1024*1024
    const int n = idx >> 10, k = idx & 1023;
    WT[idx] = __float2bfloat16(W[(size_t)k * ld + n]);
}

// ---------------------------------------------------------------------------
// Pure-bf16 GEMM: C = A @ BT^T (+bias). A [M][K], BT [N][K], both bf16.
// 128x128 tile (m97-class), 4 waves of 64x64, BK=32, double-buffered LDS,
// one barrier/iter, register prefetch. 16 MFMA per 8 ds_read_b128 per wave.
// ---------------------------------------------------------------------------
template <typename CT>
__global__ __launch_bounds__(256) void gemm_bf_kernel(
    const __hip_bfloat16* __restrict__ A,
    const __hip_bfloat16* __restrict__ BT,
    const float* __restrict__ bias,   // may be null
    CT* __restrict__ C, int M, int N, int K) {
    __shared__ __align__(16) __hip_bfloat16 As[2][128][40];
    __shared__ __align__(16) __hip_bfloat16 Bs[2][128][40];

    const int tid  = threadIdx.x;
    const int lane = tid & 63, wid = tid >> 6;
    const int wm   = wid >> 1, wn = wid & 1;
    const int quad = lane >> 4, l15 = lane & 15;
    const int bm = blockIdx.y * 128, bn = blockIdx.x * 128;

    floatx4 acc[4][4];
#pragma unroll
    for (int r = 0; r < 4; r++)
#pragma unroll
        for (int c = 0; c < 4; c++) acc[r][c] = (floatx4){0.f, 0.f, 0.f, 0.f};

    short8 ra[2], rb[2];
    auto load_tile = [&](int k0) {
#pragma unroll
        for (int r = 0; r < 2; r++) {
            const int c = r * 256 + tid;       // 0..511 over 128x32/8
            ra[r] = *(const short8*)(A  + (size_t)(bm + (c >> 2)) * K + k0 + (c & 3) * 8);
            rb[r] = *(const short8*)(BT + (size_t)(bn + (c >> 2)) * K + k0 + (c & 3) * 8);
        }
    };
    auto store_tile = [&](int buf) {
#pragma unroll
        for (int r = 0; r < 2; r++) {
            const int c = r * 256 + tid;
            *(short8*)&As[buf][c >> 2][(c & 3) * 8] = ra[r];
            *(short8*)&Bs[buf][c >> 2][(c & 3) * 8] = rb[r];
        }
    };

    load_tile(0);
    store_tile(0);
    if (K > 32) load_tile(32);
    __syncthreads();

    const int nk = K >> 5;
    for (int kb = 0; kb < nk; ++kb) {
        const int buf = kb & 1;
        if (kb + 1 < nk) store_tile(buf ^ 1);
        if (kb + 2 < nk) load_tile((kb + 2) << 5);

        short8 af[4], bf[4];
#pragma unroll
        for (int r = 0; r < 4; r++)
            af[r] = *(const short8*)&As[buf][wm * 64 + r * 16 + l15][quad * 8];
#pragma unroll
        for (int c = 0; c < 4; c++)
            bf[c] = *(const short8*)&Bs[buf][wn * 64 + c * 16 + l15][quad * 8];
#pragma unroll
        for (int r = 0; r < 4; r++)
#pragma unroll
            for (int c = 0; c < 4; c++)
                acc[r][c] = MFMA16(af[r], bf[c], acc[r][c]);
        __syncthreads();
    }

#pragma unroll
    for (int c = 0; c < 4; c++) {
        const int col = bn + wn * 64 + c * 16 + l15;
        const float bv = bias ? bias[col] : 0.f;
#pragma unroll
        for (int r = 0; r < 4; r++) {
            const int row0 = bm + wm * 64 + r * 16 + quad * 4;
#pragma unroll
            for (int i = 0; i < 4; i++) {
                const float v = acc[r][c][i] + bv;
                if constexpr (__is_same(CT, float))
                    C[(size_t)(row0 + i) * N + col] = v;
                else
                    C[(size_t)(row0 + i) * N + col] = __float2bfloat16(v);
            }
        }
    }
}

// ---------------------------------------------------------------------------
// Fallback GEMM (fp32 inputs, in-LDS transpose) — only if ws is small.
// ---------------------------------------------------------------------------
template <typename AT, typename CT>
__global__ __launch_bounds__(256) void gemm_fp_kernel(
    const AT* __restrict__ A, const float* __restrict__ B,
    const float* __restrict__ bias, CT* __restrict__ C,
    int M, int N, int K, int ldb) {
    __shared__ __align__(16) __hip_bfloat16 As[2][64][40];
    __shared__ __align__(16) __hip_bfloat16 Bs[2][128][40];
    const int tid = threadIdx.x;
    const int lane = tid & 63, wid = tid >> 6;
    const int wm = wid >> 1, wn = wid & 1;
    const int quad = lane >> 4, l15 = lane & 15;
    const int bm = blockIdx.y * 64, bn = blockIdx.x * 128;
    floatx4 acc[2][4];
#pragma unroll
    for (int r = 0; r < 2; r++)
#pragma unroll
        for (int c = 0; c < 4; c++) acc[r][c] = (floatx4){0.f, 0.f, 0.f, 0.f};
    const int a_lr = tid >> 2, a_lc = (tid & 3) * 8;
    const int b_kr = tid & 31, b_nc = (tid >> 5) * 16;
    floatx4 raf0, raf1; short8 rab; floatx4 rb[4];
    auto load_tile = [&](int k0) {
        const AT* pa = A + (size_t)(bm + a_lr) * K + k0 + a_lc;
        if constexpr (__is_same(AT, float)) {
            raf0 = *(const floatx4*)pa; raf1 = *(const floatx4*)(pa + 4);
        } else { rab = *(const short8*)pa; }
        const float* pb = B + (size_t)(k0 + b_kr) * ldb + bn + b_nc;
#pragma unroll
        for (int q = 0; q < 4; q++) rb[q] = *(const floatx4*)(pb + 4 * q);
    };
    auto store_tile = [&](int buf) {
        if constexpr (__is_same(AT, float)) {
            __align__(16) __hip_bfloat16 hh[8];
#pragma unroll
            for (int j = 0; j < 4; j++) {
                hh[j] = __float2bfloat16(raf0[j]); hh[4 + j] = __float2bfloat16(raf1[j]);
            }
            *(short8*)&As[buf][a_lr][a_lc] = *(short8*)&hh[0];
        } else { *(short8*)&As[buf][a_lr][a_lc] = rab; }
#pragma unroll
        for (int q = 0; q < 4; q++)
#pragma unroll
            for (int j = 0; j < 4; j++)
                Bs[buf][b_nc + 4 * q + j][b_kr] = __float2bfloat16(rb[q][j]);
    };
    load_tile(0); store_tile(0);
    if (K > 32) load_tile(32);
    __syncthreads();
    const int nk = K >> 5;
    for (int kb = 0; kb < nk; ++kb) {
        const int buf = kb & 1;
        if (kb + 1 < nk) store_tile(buf ^ 1);
        if (kb + 2 < nk) load_tile((kb + 2) << 5);
        short8 af[2], bf[4];
#pragma unroll
        for (int r = 0; r < 2; r++)
            af[r] = *(const short8*)&As[buf][wm * 32 + r * 16 + l15][quad * 8];
#pragma unroll
        for (int c = 0; c < 4; c++)
            bf[c] = *(const short8*)&Bs[buf][wn * 64 + c * 16 + l15][quad * 8];
#pragma unroll
        for (int r = 0; r < 2; r++)
#pragma unroll
            for (int c = 0; c < 4; c++)
                acc[r][c] = MFMA16(af[r], bf[c], acc[r][c]);
        __syncthreads();
    }
#pragma unroll
    for (int c = 0; c < 4; c++) {
        const int col = bn + wn * 64 + c * 16 + l15;
        const float bv = bias ? bias[col] : 0.f;
#pragma unroll
        for (int r = 0; r < 2; r++) {
            const int row0 = bm + wm * 32 + r * 16 + quad * 4;
#pragma unroll
            for (int i = 0; i < 4; i++) {
                const float v = acc[r][c][i] + bv;
                if constexpr (__is_same(CT, float)) C[(size_t)(row0 + i) * N + col] = v;
                else C[(size_t)(row0 + i) * N + col] = __float2bfloat16(v);
            }
        }
    }
}

// ---------------------------------------------------------------------------
// Causal flash attention, q = k = v = T[:, h*64:(h+1)*64] (bf16 in/out).
// 128 Q rows/block (4 waves x 32). S^T = K·Q^T so that P^T's C-layout
// (q=l15, key=quad*4+i) IS the A-operand layout of 16x16x16 MFMA -> PV needs
// NO LDS roundtrip for P. Fixed-max softmax, double-buffered K/V, 1 barrier.
// ---------------------------------------------------------------------------
__global__ __launch_bounds__(256) void attn_kernel(
    const __hip_bfloat16* __restrict__ T,   // [4096][1024]
    __hip_bfloat16* __restrict__ O) {       // [4096][1024]
#if HAVE_PV16
    __shared__ __align__(16) __hip_bfloat16 Ks[2][64][68];  // K rows [key][d]
    __shared__ __align__(16) __hip_bfloat16 Vt[2][64][68];  // V^T    [d][key]

    const int tid  = threadIdx.x;
    const int lane = tid & 63, wid = tid >> 6;
    const int quad = lane >> 4, l15 = lane & 15;

    const int qt = 15 - blockIdx.x;  // longest blocks dispatch first
    const int h  = blockIdx.y;
    const int b  = blockIdx.z;

    const size_t rowbase = (size_t)b * SEQ;
    const int hoff = h * DHEAD;
    const int qrow0 = qt * 128;
    const int wave_min_q = qrow0 + wid * 32;

    // Q fragments (B-operand of S^T: n=q=l15, k=d=quad*8+j) — same layout
    short8 qf[2][2];
#pragma unroll
    for (int rt = 0; rt < 2; rt++) {
        const __hip_bfloat16* qp =
            T + (rowbase + qrow0 + wid * 32 + rt * 16 + l15) * DIMM + hoff + quad * 8;
        qf[rt][0] = *(const short8*)qp;
        qf[rt][1] = *(const short8*)(qp + 32);
    }

    float l_lane[2] = {0.f, 0.f};            // per-lane partial sum (q=l15)
    floatx4 accO[2][4];                      // [rt][dtile]: row q=quad*4+i, col d=l15
#pragma unroll
    for (int rt = 0; rt < 2; rt++)
#pragma unroll
        for (int dt = 0; dt < 4; dt++) accO[rt][dt] = (floatx4){0.f,0.f,0.f,0.f};

    // staging maps
    const int lr1   = tid >> 2;         // Ks row   0..63
    const int lc1   = (tid & 3) * 16;   // Ks d-seg
    const int key2  = tid & 63;         // Vt key   0..63
    const int dseg2 = (tid >> 6) * 16;  // Vt d-seg

    short8 rA0, rA1, rB0, rB1;
    auto load_tile = [&](int kt) {
        const __hip_bfloat16* pa = T + (rowbase + kt * 64 + lr1) * DIMM + hoff + lc1;
        rA0 = *(const short8*)pa; rA1 = *(const short8*)(pa + 8);
        const __hip_bfloat16* pb = T + (rowbase + kt * 64 + key2) * DIMM + hoff + dseg2;
        rB0 = *(const short8*)pb; rB1 = *(const short8*)(pb + 8);
    };
    auto store_tile = [&](int buf) {
        *(short8*)&Ks[buf][lr1][lc1]     = rA0;
        *(short8*)&Ks[buf][lr1][lc1 + 8] = rA1;
#pragma unroll
        for (int j = 0; j < 8; j++) {
            Vt[buf][dseg2 + j][key2]     = ((const __hip_bfloat16*)&rB0)[j];
            Vt[buf][dseg2 + 8 + j][key2] = ((const __hip_bfloat16*)&rB1)[j];
        }
    };

    const int last = 2 * qt + 1;
    load_tile(0);
    store_tile(0);
    if (last >= 1) load_tile(1);
    __syncthreads();

    for (int kt = 0; kt <= last; ++kt) {
        const int buf = kt & 1;
        if (kt < last)      store_tile(buf ^ 1);
        if (kt + 2 <= last) load_tile(kt + 2);

        if (kt * 64 <= wave_min_q + 31) {
            // S^T = K Q^T : A = K rows (m=key=l15, k=d), B = Q (n=q=l15)
            // C-layout: lane holds (key = c*16 + quad*4 + i, q = l15)
            floatx4 s[2][4];
#pragma unroll
            for (int c = 0; c < 4; c++) {
#pragma unroll
                for (int rt = 0; rt < 2; rt++) s[rt][c] = (floatx4){0.f,0.f,0.f,0.f};
#pragma unroll
                for (int ks = 0; ks < 2; ks++) {
                    short8 kfr = *(const short8*)&Ks[buf][c * 16 + l15][ks * 32 + quad * 8];
#pragma unroll
                    for (int rt = 0; rt < 2; rt++)
                        s[rt][c] = MFMA16(kfr, qf[rt][ks], s[rt][c]);
                }
            }

            // p^T = exp2(s*K1 + K2), causal-masked; pack in-register to
            // 16x16x16 A-frags (m=q=l15, k=key=quad*4+j) — the identity.
            bf16x4 pk[2][4];
            const bool need_mask = (kt * 64 + 63 > wave_min_q);
#pragma unroll
            for (int rt = 0; rt < 2; rt++) {
#pragma unroll
                for (int c = 0; c < 4; c++) {
                    union { bf16x4 v; __hip_bfloat16 hh[4]; } u;
                    float sum = 0.f;
#pragma unroll
                    for (int i = 0; i < 4; i++) {
                        float v = exp2f(fmaf(s[rt][c][i], K1, K2));
                        if (need_mask) {
                            const int key  = kt * 64 + c * 16 + quad * 4 + i;
                            const int qrow = wave_min_q + rt * 16 + l15;
                            if (key > qrow) v = 0.f;
                        }
                        sum += v;
                        u.hh[i] = __float2bfloat16(v);
                    }
                    l_lane[rt] += sum;
                    pk[rt][c] = u.v;
                }
            }

            // O += P V : B-frag (k=key=quad*4+j, n=d=l15) = Vt[dt*16+l15][c*16+quad*4]
#pragma unroll
            for (int c = 0; c < 4; c++) {
#pragma unroll
                for (int dt = 0; dt < 4; dt++) {
                    bf16x4 vb = *(const bf16x4*)&Vt[buf][dt * 16 + l15][c * 16 + quad * 4];
#pragma unroll
                    for (int rt = 0; rt < 2; rt++)
                        accO[rt][dt] = MFMA_PV(pk[rt][c], vb, accO[rt][dt]);
                }
            }
        }
        __syncthreads();
    }

    // l lives per lane at q=l15: reduce across the 4 quads
#pragma unroll
    for (int rt = 0; rt < 2; rt++) {
        l_lane[rt] += __shfl_xor(l_lane[rt], 16);
        l_lane[rt] += __shfl_xor(l_lane[rt], 32);
    }
    // redistribute: output rows are q = quad*4+i -> fetch l from lane quad*4+i
#pragma unroll
    for (int rt = 0; rt < 2; rt++) {
        float inv[4];
#pragma unroll
        for (int i = 0; i < 4; i++)
            inv[i] = 1.f / __shfl(l_lane[rt], quad * 4 + i, 64);
#pragma unroll
        for (int dt = 0; dt < 4; dt++)
#pragma unroll
            for (int i = 0; i < 4; i++) {
                const size_t row = rowbase + qrow0 + wid * 32 + rt * 16 + quad * 4 + i;
                O[row * DIMM + hoff + dt * 16 + l15] =
                    __float2bfloat16(accO[rt][dt][i] * inv[i]);
            }
    }
#else  // ------- fallback: R7 Ps-roundtrip path (no 16x16x16 builtin) -------
    __shared__ __align__(16) __hip_bfloat16 Ks[2][64][68];
    __shared__ __align__(16) __hip_bfloat16 Vt[2][64][68];
    __shared__ __align__(16) __hip_bfloat16 Ps[128][68];

    const int tid  = threadIdx.x;
    const int lane = tid & 63, wid = tid >> 6;
    const int quad = lane >> 4, l15 = lane & 15;
    const int qt = 15 - blockIdx.x;
    const int h  = blockIdx.y;
    const int b  = blockIdx.z;
    const size_t rowbase = (size_t)b * SEQ;
    const int hoff = h * DHEAD;
    const int qrow0 = qt * 128;
    const int wave_min_q = qrow0 + wid * 32;

    short8 qf[2][2];
#pragma unroll
    for (int rt = 0; rt < 2; rt++) {
        const __hip_bfloat16* qp =
            T + (rowbase + qrow0 + wid * 32 + rt * 16 + l15) * DIMM + hoff + quad * 8;
        qf[rt][0] = *(const short8*)qp;
        qf[rt][1] = *(const short8*)(qp + 32);
    }
    float l_i[2][4] = {{0.f,0.f,0.f,0.f},{0.f,0.f,0.f,0.f}};
    floatx4 accO[2][4];
#pragma unroll
    for (int rt = 0; rt < 2; rt++)
#pragma unroll
        for (int c = 0; c < 4; c++) accO[rt][c] = (floatx4){0.f,0.f,0.f,0.f};
    const int lr1 = tid >> 2, lc1 = (tid & 3) * 16;
    const int key2 = tid & 63, dseg2 = (tid >> 6) * 16;
    short8 rA0, rA1, rB0, rB1;
    auto load_tile = [&](int kt) {
        const __hip_bfloat16* pa = T + (rowbase + kt * 64 + lr1) * DIMM + hoff + lc1;
        rA0 = *(const short8*)pa; rA1 = *(const short8*)(pa + 8);
        const __hip_bfloat16* pb = T + (rowbase + kt * 64 + key2) * DIMM + hoff + dseg2;
        rB0 = *(const short8*)pb; rB1 = *(const short8*)(pb + 8);
    };
    auto store_tile = [&](int buf) {
        *(short8*)&Ks[buf][lr1][lc1]     = rA0;
        *(short8*)&Ks[buf][lr1][lc1 + 8] = rA1;
#pragma unroll
        for (int j = 0; j < 8; j++) {
            Vt[buf][dseg2 + j][key2]     = ((const __hip_bfloat16*)&rB0)[j];
            Vt[buf][dseg2 + 8 + j][key2] = ((const __hip_bfloat16*)&rB1)[j];
        }
    };
    const int last = 2 * qt + 1;
    load_tile(0); store_tile(0);
    if (last >= 1) load_tile(1);
    __syncthreads();
    for (int kt = 0; kt <= last; ++kt) {
        const int buf = kt & 1;
        if (kt < last)      store_tile(buf ^ 1);
        if (kt + 2 <= last) load_tile(kt + 2);
        if (kt * 64 <= wave_min_q + 31) {
            floatx4 s[2][4];
#pragma unroll
            for (int c = 0; c < 4; c++) {
#pragma unroll
                for (int rt = 0; rt < 2; rt++) s[rt][c] = (floatx4){0.f,0.f,0.f,0.f};
#pragma unroll
                for (int ks = 0; ks < 2; ks++) {
                    short8 bfr = *(const short8*)&Ks[buf][c * 16 + l15][ks * 32 + quad * 8];
#pragma unroll
                    for (int rt = 0; rt < 2; rt++)
                        s[rt][c] = MFMA16(qf[rt][ks], bfr, s[rt][c]);
                }
            }
            float p[2][4][4];
            const bool need_mask = (kt * 64 + 63 > wave_min_q);
#pragma unroll
            for (int c = 0; c < 4; c++) {
                const int key = kt * 64 + c * 16 + l15;
#pragma unroll
                for (int rt = 0; rt < 2; rt++)
#pragma unroll
                    for (int i = 0; i < 4; i++) {
                        float v = exp2f(fmaf(s[rt][c][i], K1, K2));
                        if (need_mask) {
                            const int qrow = wave_min_q + rt * 16 + quad * 4 + i;
                            if (key > qrow) v = 0.f;
                        }
                        p[rt][c][i] = v;
                    }
            }
#pragma unroll
            for (int rt = 0; rt < 2; rt++)
#pragma unroll
                for (int i = 0; i < 4; i++)
                    l_i[rt][i] += (p[rt][0][i] + p[rt][1][i]) + (p[rt][2][i] + p[rt][3][i]);
#pragma unroll
            for (int rt = 0; rt < 2; rt++)
#pragma unroll
                for (int c = 0; c < 4; c++)
#pragma unroll
                    for (int i = 0; i < 4; i++)
                        Ps[wid * 32 + rt * 16 + quad * 4 + i][c * 16 + l15] =
                            __float2bfloat16(p[rt][c][i]);
#pragma unroll
            for (int c = 0; c < 4; c++)
#pragma unroll
                for (int ks = 0; ks < 2; ks++) {
                    short8 bfr = *(const short8*)&Vt[buf][c * 16 + l15][ks * 32 + quad * 8];
#pragma unroll
                    for (int rt = 0; rt < 2; rt++) {
                        short8 afr = *(const short8*)&Ps[wid * 32 + rt * 16 + l15][ks * 32 + quad * 8];
                        accO[rt][c] = MFMA16(afr, bfr, accO[rt][c]);
                    }
                }
        }
        __syncthreads();
    }
#pragma unroll
    for (int off = 1; off < 16; off <<= 1)
#pragma unroll
        for (int rt = 0; rt < 2; rt++)
#pragma unroll
            for (int i = 0; i < 4; i++) l_i[rt][i] += __shfl_xor(l_i[rt][i], off);
#pragma unroll
    for (int rt = 0; rt < 2; rt++) {
        float inv[4];
#pragma unroll
        for (int i = 0; i < 4; i++) inv[i] = 1.f / l_i[rt][i];
#pragma unroll
        for (int c = 0; c < 4; c++)
#pragma unroll
            for (int i = 0; i < 4; i++) {
                const size_t row = rowbase + qrow0 + wid * 32 + rt * 16 + quad * 4 + i;
                O[row * DIMM + hoff + c * 16 + l15] =
                    __float2bfloat16(accO[rt][c][i] * inv[i]);
            }
    }
#endif
}

// ---------------------------------------------------------------------------
extern "C" void kernel_launch(void* const* d_in, const int* in_sizes, int n_in,
                              void* d_out, int out_size, void* d_ws, size_t ws_size,
                              hipStream_t stream) {
    const float* x     = (const float*)d_in[0];  // [2,2048,1024] fp32
    const float* w_qkv = (const float*)d_in[1];  // [1024,3072]   fp32
    const float* w_out = (const float*)d_in[2];  // [1024,1024]   fp32
    const float* b_out = (const float*)d_in[3];  // [1024]        fp32
    float* out = (float*)d_out;                  // [2,2048,1024] fp32

    // t (bf16 activation) in d_out[0,8MiB) (dead before final GEMM writes out).
    __hip_bfloat16* t  = (__hip_bfloat16*)d_out;
    char* ws = (char*)d_ws;
    __hip_bfloat16* ob = (__hip_bfloat16*)ws;    // [0,8 MiB) both paths

    if (ws_size >= (size_t)(20u << 20)) {
        __hip_bfloat16* xb  = (__hip_bfloat16*)(ws + (8u  << 20)); // 8 MiB
        __hip_bfloat16* w1t = (__hip_bfloat16*)(ws + (16u << 20)); // 2 MiB
        __hip_bfloat16* w2t = (__hip_bfloat16*)(ws + (18u << 20)); // 2 MiB

        cvt_bf16_kernel<<<4096, 256, 0, stream>>>(x, xb);
        transpose_cvt_kernel<<<4096, 256, 0, stream>>>(w_qkv, w1t, 3 * DIMM);
        transpose_cvt_kernel<<<4096, 256, 0, stream>>>(w_out, w2t, DIMM);

        gemm_bf_kernel<__hip_bfloat16><<<dim3(8, 32), 256, 0, stream>>>(
            xb, w1t, nullptr, t, ROWS, DIMM, DIMM);
        attn_kernel<<<dim3(16, HEADS, 2), 256, 0, stream>>>(t, ob);
        gemm_bf_kernel<float><<<dim3(8, 32), 256, 0, stream>>>(
            ob, w2t, b_out, out, ROWS, DIMM, DIMM);
    } else {
        gemm_fp_kernel<float, __hip_bfloat16><<<dim3(8, 64), 256, 0, stream>>>(
            x, w_qkv, nullptr, t, ROWS, DIMM, DIMM, 3 * DIMM);
        attn_kernel<<<dim3(16, HEADS, 2), 256, 0, stream>>>(t, ob);
        gemm_fp_kernel<__hip_bfloat16, float><<<dim3(8, 64), 256, 0, stream>>>(
            ob, w_out, b_out, out, ROWS, DIMM, DIMM, DIMM);
    }
}

// Round 11
// 196.903 us; speedup vs baseline: 1.1804x; 1.1804x over previous
//
#include <hip/hip_runtime.h>
#include <hip/hip_bf16.h>

typedef __attribute__((ext_vector_type(8))) short short8;
typedef __attribute__((ext_vector_type(4))) short bf16x4;
typedef __attribute__((ext_vector_type(4))) float floatx4;

#define MFMA16(a, b, c) __builtin_amdgcn_mfma_f32_16x16x32_bf16((a), (b), (c), 0, 0, 0)

#if defined(__HIP_DEVICE_COMPILE__)
  #if __has_builtin(__builtin_amdgcn_mfma_f32_16x16x16bf16_1k)
    #define MFMA_PV(a, b, c) __builtin_amdgcn_mfma_f32_16x16x16bf16_1k((a), (b), (c), 0, 0, 0)
  #elif __has_builtin(__builtin_amdgcn_mfma_f32_16x16x16_bf16)
    #define MFMA_PV(a, b, c) __builtin_amdgcn_mfma_f32_16x16x16_bf16((a), (b), (c), 0, 0, 0)
  #else
    #error "no 16x16x16 bf16 MFMA builtin found on device pass"
  #endif
#else
  // host pass: device builtins invisible; this is never executed on host
  #define MFMA_PV(a, b, c) (c)
#endif

#define SEQ    2048
#define DIMM   1024
#define HEADS  16
#define DHEAD  64
#define ROWS   4096      // b*n = 2*2048
// fixed-max softmax: p = exp2(s*K1 + K2), K1 = 0.125*log2(e), K2 = -24*log2(e)
#define K1 0.18033688011112043f
#define K2 (-34.62468098133512f)

// ---------------------------------------------------------------------------
// Prep kernels.
// ---------------------------------------------------------------------------
__global__ void cvt_bf16_kernel(const float* __restrict__ src,
                                __hip_bfloat16* __restrict__ dst) {
    const size_t i = (size_t)(blockIdx.x * 256 + threadIdx.x) * 4;
    floatx4 v = *(const floatx4*)(src + i);
    union { bf16x4 s; __hip_bfloat16 h[4]; } u;
#pragma unroll
    for (int j = 0; j < 4; j++) u.h[j] = __float2bfloat16(v[j]);
    *(bf16x4*)(dst + i) = u.s;
}

__global__ void transpose_cvt_kernel(const float* __restrict__ W,
                                     __hip_bfloat16* __restrict__ WT, int ld) {
    const int idx = blockIdx.x * 256 + threadIdx.x;   // over 1024*1024
    const int n = idx >> 10, k = idx & 1023;
    WT[idx] = __float2bfloat16(W[(size_t)k * ld + n]);
}

// bf16 [4096][1024] -> [1024][4096], LDS-tiled 64x64, coalesced both sides
__global__ __launch_bounds__(256) void transpose_t_kernel(
    const __hip_bfloat16* __restrict__ t,
    __hip_bfloat16* __restrict__ Tt) {
    __shared__ __hip_bfloat16 tile[64][72];
    const int tid = threadIdx.x;
    const int r = tid >> 2, c0 = (tid & 3) * 16;
    const int row0 = blockIdx.x * 64;   // t-row tile 0..63
    const int col0 = blockIdx.y * 64;   // t-col tile 0..15
    const __hip_bfloat16* src = t + (size_t)(row0 + r) * DIMM + col0 + c0;
    *(short8*)&tile[r][c0]     = *(const short8*)src;
    *(short8*)&tile[r][c0 + 8] = *(const short8*)(src + 8);
    __syncthreads();
    union { short8 v; __hip_bfloat16 h[8]; } u0, u1;
#pragma unroll
    for (int j = 0; j < 8; j++) {
        u0.h[j] = tile[c0 + j][r];
        u1.h[j] = tile[c0 + 8 + j][r];
    }
    __hip_bfloat16* dst = Tt + (size_t)(col0 + r) * ROWS + row0 + c0;
    *(short8*)dst       = u0.v;
    *(short8*)(dst + 8) = u1.v;
}

// ---------------------------------------------------------------------------
// Pure-bf16 GEMM: C = A @ BT^T (+bias). 64x128 tile, BK=64, dbuf (55 KiB ->
// 2 blocks/CU at grid 512), reordered loop: compute BEFORE vmcnt-gated store.
// ---------------------------------------------------------------------------
template <typename CT>
__global__ __launch_bounds__(256) void gemm_bf_kernel(
    const __hip_bfloat16* __restrict__ A,
    const __hip_bfloat16* __restrict__ BT,
    const float* __restrict__ bias,   // may be null
    CT* __restrict__ C, int M, int N, int K) {
    __shared__ __align__(16) __hip_bfloat16 As[2][64][72];
    __shared__ __align__(16) __hip_bfloat16 Bs[2][128][72];

    const int tid  = threadIdx.x;
    const int lane = tid & 63, wid = tid >> 6;
    const int wm   = wid >> 1, wn = wid & 1;
    const int quad = lane >> 4, l15 = lane & 15;
    const int bm = blockIdx.y * 64, bn = blockIdx.x * 128;

    floatx4 acc[2][4];
#pragma unroll
    for (int r = 0; r < 2; r++)
#pragma unroll
        for (int c = 0; c < 4; c++) acc[r][c] = (floatx4){0.f, 0.f, 0.f, 0.f};

    // staging maps: A 16 elem/thread (2 short8), B 32 elem/thread (4 short8)
    const int ar = tid >> 2, ac = (tid & 3) * 16;
    short8 ra[2], rb[4];
    auto load_tile = [&](int k0) {
        const __hip_bfloat16* pa = A + (size_t)(bm + ar) * K + k0 + ac;
        ra[0] = *(const short8*)pa; ra[1] = *(const short8*)(pa + 8);
#pragma unroll
        for (int r = 0; r < 2; r++) {
            const int c2 = r * 256 + tid;
            const __hip_bfloat16* pb =
                BT + (size_t)(bn + (c2 >> 2)) * K + k0 + (c2 & 3) * 16;
            rb[2 * r]     = *(const short8*)pb;
            rb[2 * r + 1] = *(const short8*)(pb + 8);
        }
    };
    auto store_tile = [&](int buf) {
        *(short8*)&As[buf][ar][ac]     = ra[0];
        *(short8*)&As[buf][ar][ac + 8] = ra[1];
#pragma unroll
        for (int r = 0; r < 2; r++) {
            const int c2 = r * 256 + tid;
            *(short8*)&Bs[buf][c2 >> 2][(c2 & 3) * 16]     = rb[2 * r];
            *(short8*)&Bs[buf][c2 >> 2][(c2 & 3) * 16 + 8] = rb[2 * r + 1];
        }
    };

    load_tile(0);
    store_tile(0);
    if (K > 64) load_tile(64);
    __syncthreads();

    const int nk = K >> 6;
    for (int kb = 0; kb < nk; ++kb) {
        const int buf = kb & 1;
        // compute first (reads staged last iter): global latency overlaps this
#pragma unroll
        for (int ks = 0; ks < 2; ks++) {
            short8 af[2], bf[4];
#pragma unroll
            for (int r = 0; r < 2; r++)
                af[r] = *(const short8*)&As[buf][wm * 32 + r * 16 + l15][ks * 32 + quad * 8];
#pragma unroll
            for (int c = 0; c < 4; c++)
                bf[c] = *(const short8*)&Bs[buf][wn * 64 + c * 16 + l15][ks * 32 + quad * 8];
#pragma unroll
            for (int r = 0; r < 2; r++)
#pragma unroll
                for (int c = 0; c < 4; c++)
                    acc[r][c] = MFMA16(af[r], bf[c], acc[r][c]);
        }
        if (kb + 1 < nk) store_tile(buf ^ 1);
        if (kb + 2 < nk) load_tile((kb + 2) << 6);
        __syncthreads();
    }

#pragma unroll
    for (int c = 0; c < 4; c++) {
        const int col = bn + wn * 64 + c * 16 + l15;
        const float bv = bias ? bias[col] : 0.f;
#pragma unroll
        for (int r = 0; r < 2; r++) {
            const int row0 = bm + wm * 32 + r * 16 + quad * 4;
#pragma unroll
            for (int i = 0; i < 4; i++) {
                const float v = acc[r][c][i] + bv;
                if constexpr (__is_same(CT, float))
                    C[(size_t)(row0 + i) * N + col] = v;
                else
                    C[(size_t)(row0 + i) * N + col] = __float2bfloat16(v);
            }
        }
    }
}

// ---------------------------------------------------------------------------
// Fallback GEMM (fp32 inputs, in-LDS transpose) — only if ws is tiny.
// ---------------------------------------------------------------------------
template <typename AT, typename CT>
__global__ __launch_bounds__(256) void gemm_fp_kernel(
    const AT* __restrict__ A, const float* __restrict__ B,
    const float* __restrict__ bias, CT* __restrict__ C,
    int M, int N, int K, int ldb) {
    __shared__ __align__(16) __hip_bfloat16 As[2][64][40];
    __shared__ __align__(16) __hip_bfloat16 Bs[2][128][40];
    const int tid = threadIdx.x;
    const int lane = tid & 63, wid = tid >> 6;
    const int wm = wid >> 1, wn = wid & 1;
    const int quad = lane >> 4, l15 = lane & 15;
    const int bm = blockIdx.y * 64, bn = blockIdx.x * 128;
    floatx4 acc[2][4];
#pragma unroll
    for (int r = 0; r < 2; r++)
#pragma unroll
        for (int c = 0; c < 4; c++) acc[r][c] = (floatx4){0.f, 0.f, 0.f, 0.f};
    const int a_lr = tid >> 2, a_lc = (tid & 3) * 8;
    const int b_kr = tid & 31, b_nc = (tid >> 5) * 16;
    floatx4 raf0, raf1; short8 rab; floatx4 rb[4];
    auto load_tile = [&](int k0) {
        const AT* pa = A + (size_t)(bm + a_lr) * K + k0 + a_lc;
        if constexpr (__is_same(AT, float)) {
            raf0 = *(const floatx4*)pa; raf1 = *(const floatx4*)(pa + 4);
        } else { rab = *(const short8*)pa; }
        const float* pb = B + (size_t)(k0 + b_kr) * ldb + bn + b_nc;
#pragma unroll
        for (int q = 0; q < 4; q++) rb[q] = *(const floatx4*)(pb + 4 * q);
    };
    auto store_tile = [&](int buf) {
        if constexpr (__is_same(AT, float)) {
            __align__(16) __hip_bfloat16 hh[8];
#pragma unroll
            for (int j = 0; j < 4; j++) {
                hh[j] = __float2bfloat16(raf0[j]); hh[4 + j] = __float2bfloat16(raf1[j]);
            }
            *(short8*)&As[buf][a_lr][a_lc] = *(short8*)&hh[0];
        } else { *(short8*)&As[buf][a_lr][a_lc] = rab; }
#pragma unroll
        for (int q = 0; q < 4; q++)
#pragma unroll
            for (int j = 0; j < 4; j++)
                Bs[buf][b_nc + 4 * q + j][b_kr] = __float2bfloat16(rb[q][j]);
    };
    load_tile(0); store_tile(0);
    if (K > 32) load_tile(32);
    __syncthreads();
    const int nk = K >> 5;
    for (int kb = 0; kb < nk; ++kb) {
        const int buf = kb & 1;
        short8 af[2], bf[4];
#pragma unroll
        for (int r = 0; r < 2; r++)
            af[r] = *(const short8*)&As[buf][wm * 32 + r * 16 + l15][quad * 8];
#pragma unroll
        for (int c = 0; c < 4; c++)
            bf[c] = *(const short8*)&Bs[buf][wn * 64 + c * 16 + l15][quad * 8];
#pragma unroll
        for (int r = 0; r < 2; r++)
#pragma unroll
            for (int c = 0; c < 4; c++)
                acc[r][c] = MFMA16(af[r], bf[c], acc[r][c]);
        if (kb + 1 < nk) store_tile(buf ^ 1);
        if (kb + 2 < nk) load_tile((kb + 2) << 5);
        __syncthreads();
    }
#pragma unroll
    for (int c = 0; c < 4; c++) {
        const int col = bn + wn * 64 + c * 16 + l15;
        const float bv = bias ? bias[col] : 0.f;
#pragma unroll
        for (int r = 0; r < 2; r++) {
            const int row0 = bm + wm * 32 + r * 16 + quad * 4;
#pragma unroll
            for (int i = 0; i < 4; i++) {
                const float v = acc[r][c][i] + bv;
                if constexpr (__is_same(CT, float)) C[(size_t)(row0 + i) * N + col] = v;
                else C[(size_t)(row0 + i) * N + col] = __float2bfloat16(v);
            }
        }
    }
}

// ---------------------------------------------------------------------------
// Causal flash attention, q = k = v = T[:, h*64:(h+1)*64].
// 128 Q rows/block. S^T = K Q^T -> P packs in-register to 16x16x16 A-frags
// (no P LDS roundtrip). V^T staged by VECTOR loads from pre-transposed Tt
// (no scalar-transpose staging). Compute-before-store loop order; balanced
// dispatch: blocks i and i+256 carry complementary qt.
// ---------------------------------------------------------------------------
__global__ __launch_bounds__(256) void attn_kernel(
    const __hip_bfloat16* __restrict__ T,    // [4096][1024]
    const __hip_bfloat16* __restrict__ Tt,   // [1024][4096]
    __hip_bfloat16* __restrict__ O) {        // [4096][1024]
    __shared__ __align__(16) __hip_bfloat16 Ks[2][64][68];  // K rows [key][d]
    __shared__ __align__(16) __hip_bfloat16 Vt[2][64][68];  // V^T    [d][key]

    const int tid  = threadIdx.x;
    const int lane = tid & 63, wid = tid >> 6;
    const int quad = lane >> 4, l15 = lane & 15;

    // balanced decode: block i and i+256 sum to uniform 34 iters
    const int bx = blockIdx.x;
    const int half = bx >> 8, idx = bx & 255;
    const int j = idx & 7, h = (idx >> 3) & 15, b = idx >> 7;
    const int qt = half ? j : 15 - j;

    const size_t rowbase = (size_t)b * SEQ;
    const int hoff = h * DHEAD;
    const int qrow0 = qt * 128;
    const int wave_min_q = qrow0 + wid * 32;

    // Q fragments (B-operand of S^T)
    short8 qf[2][2];
#pragma unroll
    for (int rt = 0; rt < 2; rt++) {
        const __hip_bfloat16* qp =
            T + (rowbase + qrow0 + wid * 32 + rt * 16 + l15) * DIMM + hoff + quad * 8;
        qf[rt][0] = *(const short8*)qp;
        qf[rt][1] = *(const short8*)(qp + 32);
    }

    float l_lane[2] = {0.f, 0.f};
    floatx4 accO[2][4];
#pragma unroll
    for (int rt = 0; rt < 2; rt++)
#pragma unroll
        for (int dt = 0; dt < 4; dt++) accO[rt][dt] = (floatx4){0.f,0.f,0.f,0.f};

    // staging: both Ks and Vt are 2 vector loads + 2 vector stores per thread
    const int sr = tid >> 2;           // 0..63
    const int sc = (tid & 3) * 16;     // 0,16,32,48

    short8 rK0, rK1, rV0, rV1;
    auto load_tile = [&](int kt) {
        const __hip_bfloat16* pK = T + (rowbase + kt * 64 + sr) * DIMM + hoff + sc;
        rK0 = *(const short8*)pK; rK1 = *(const short8*)(pK + 8);
        const __hip_bfloat16* pV =
            Tt + (size_t)(hoff + sr) * ROWS + rowbase + kt * 64 + sc;
        rV0 = *(const short8*)pV; rV1 = *(const short8*)(pV + 8);
    };
    auto store_tile = [&](int buf) {
        *(short8*)&Ks[buf][sr][sc]     = rK0;
        *(short8*)&Ks[buf][sr][sc + 8] = rK1;
        *(short8*)&Vt[buf][sr][sc]     = rV0;
        *(short8*)&Vt[buf][sr][sc + 8] = rV1;
    };

    const int last = 2 * qt + 1;
    load_tile(0);
    store_tile(0);
    if (last >= 1) load_tile(1);
    __syncthreads();

    for (int kt = 0; kt <= last; ++kt) {
        const int buf = kt & 1;

        // ---- compute first (reads LDS staged last iter; no vmcnt dep) ----
        if (kt * 64 <= wave_min_q + 31) {
            // S^T = K Q^T; C-layout: lane (key = c*16+quad*4+i, q = l15)
            floatx4 s[2][4];
#pragma unroll
            for (int c = 0; c < 4; c++) {
#pragma unroll
                for (int rt = 0; rt < 2; rt++) s[rt][c] = (floatx4){0.f,0.f,0.f,0.f};
#pragma unroll
                for (int ks = 0; ks < 2; ks++) {
                    short8 kfr = *(const short8*)&Ks[buf][c * 16 + l15][ks * 32 + quad * 8];
#pragma unroll
                    for (int rt = 0; rt < 2; rt++)
                        s[rt][c] = MFMA16(kfr, qf[rt][ks], s[rt][c]);
                }
            }

            // p = exp2(s*K1+K2) masked; pack to 16x16x16 A-frags in-register
            bf16x4 pk[2][4];
            const bool need_mask = (kt * 64 + 63 > wave_min_q);
#pragma unroll
            for (int rt = 0; rt < 2; rt++) {
#pragma unroll
                for (int c = 0; c < 4; c++) {
                    union { bf16x4 v; __hip_bfloat16 hh[4]; } u;
                    float sum = 0.f;
#pragma unroll
                    for (int i = 0; i < 4; i++) {
                        float v = exp2f(fmaf(s[rt][c][i], K1, K2));
                        if (need_mask) {
                            const int key  = kt * 64 + c * 16 + quad * 4 + i;
                            const int qrow = wave_min_q + rt * 16 + l15;
                            if (key > qrow) v = 0.f;
                        }
                        sum += v;
                        u.hh[i] = __float2bfloat16(v);
                    }
                    l_lane[rt] += sum;
                    pk[rt][c] = u.v;
                }
            }

            // O += P V : B-frag = Vt[dt*16+l15][c*16+quad*4 ..+3]
#pragma unroll
            for (int c = 0; c < 4; c++) {
#pragma unroll
                for (int dt = 0; dt < 4; dt++) {
                    bf16x4 vb = *(const bf16x4*)&Vt[buf][dt * 16 + l15][c * 16 + quad * 4];
#pragma unroll
                    for (int rt = 0; rt < 2; rt++)
                        accO[rt][dt] = MFMA_PV(pk[rt][c], vb, accO[rt][dt]);
                }
            }
        }

        // ---- then stage next tile + prefetch ----
        if (kt < last)      store_tile(buf ^ 1);
        if (kt + 2 <= last) load_tile(kt + 2);
        __syncthreads();
    }

    // l per q=l15: reduce across quads, redistribute to C-layout rows
#pragma unroll
    for (int rt = 0; rt < 2; rt++) {
        l_lane[rt] += __shfl_xor(l_lane[rt], 16);
        l_lane[rt] += __shfl_xor(l_lane[rt], 32);
    }
#pragma unroll
    for (int rt = 0; rt < 2; rt++) {
        float inv[4];
#pragma unroll
        for (int i = 0; i < 4; i++)
            inv[i] = 1.f / __shfl(l_lane[rt], quad * 4 + i, 64);
#pragma unroll
        for (int dt = 0; dt < 4; dt++)
#pragma unroll
            for (int i = 0; i < 4; i++) {
                const size_t row = rowbase + qrow0 + wid * 32 + rt * 16 + quad * 4 + i;
                O[row * DIMM + hoff + dt * 16 + l15] =
                    __float2bfloat16(accO[rt][dt][i] * inv[i]);
            }
    }
}

// ---------------------------------------------------------------------------
extern "C" void kernel_launch(void* const* d_in, const int* in_sizes, int n_in,
                              void* d_out, int out_size, void* d_ws, size_t ws_size,
                              hipStream_t stream) {
    const float* x     = (const float*)d_in[0];  // [2,2048,1024] fp32
    const float* w_qkv = (const float*)d_in[1];  // [1024,3072]   fp32
    const float* w_out = (const float*)d_in[2];  // [1024,1024]   fp32
    const float* b_out = (const float*)d_in[3];  // [1024]        fp32
    float* out = (float*)d_out;                  // [2,2048,1024] fp32 (16 MiB)

    // t (bf16) in d_out[0,8MiB); Tt (bf16, T transposed) in d_out[8,16MiB).
    // Both dead before the final GEMM overwrites d_out.
    __hip_bfloat16* t  = (__hip_bfloat16*)d_out;
    __hip_bfloat16* Tt = (__hip_bfloat16*)((char*)d_out + (8u << 20));
    char* ws = (char*)d_ws;
    __hip_bfloat16* ob = (__hip_bfloat16*)ws;    // 8 MiB, both paths

    if (ws_size >= (size_t)(20u << 20)) {
        __hip_bfloat16* xb  = (__hip_bfloat16*)(ws + (8u  << 20)); // 8 MiB
        __hip_bfloat16* w1t = (__hip_bfloat16*)(ws + (16u << 20)); // 2 MiB
        __hip_bfloat16* w2t = (__hip_bfloat16*)(ws + (18u << 20)); // 2 MiB

        cvt_bf16_kernel<<<4096, 256, 0, stream>>>(x, xb);
        transpose_cvt_kernel<<<4096, 256, 0, stream>>>(w_qkv, w1t, 3 * DIMM);
        transpose_cvt_kernel<<<4096, 256, 0, stream>>>(w_out, w2t, DIMM);

        gemm_bf_kernel<__hip_bfloat16><<<dim3(8, 64), 256, 0, stream>>>(
            xb, w1t, nullptr, t, ROWS, DIMM, DIMM);
        transpose_t_kernel<<<dim3(64, 16), 256, 0, stream>>>(t, Tt);
        attn_kernel<<<dim3(512), 256, 0, stream>>>(t, Tt, ob);
        gemm_bf_kernel<float><<<dim3(8, 64), 256, 0, stream>>>(
            ob, w2t, b_out, out, ROWS, DIMM, DIMM);
    } else {
        gemm_fp_kernel<float, __hip_bfloat16><<<dim3(8, 64), 256, 0, stream>>>(
            x, w_qkv, nullptr, t, ROWS, DIMM, DIMM, 3 * DIMM);
        transpose_t_kernel<<<dim3(64, 16), 256, 0, stream>>>(t, Tt);
        attn_kernel<<<dim3(512), 256, 0, stream>>>(t, Tt, ob);
        gemm_fp_kernel<__hip_bfloat16, float><<<dim3(8, 64), 256, 0, stream>>>(
            ob, w_out, b_out, out, ROWS, DIMM, DIMM, DIMM);
    }
}